// Round 17
// baseline (445.274 us; speedup 1.0000x reference)
//
#include <hip/hip_runtime.h>
#include <hip/hip_fp16.h>
#include <math.h>

#define N_NODES 50000
#define N_EDGES 800000
#define NEG_SLOPE 0.2f

// ---------- helpers ----------
__device__ __forceinline__ float wred64(float v) {
#pragma unroll
    for (int off = 32; off > 0; off >>= 1) v += __shfl_xor(v, off, 64);
    return v;
}
__device__ __forceinline__ int wredi64(int v) {
#pragma unroll
    for (int off = 32; off > 0; off >>= 1) v += __shfl_xor(v, off, 64);
    return v;
}

#define SCAN_BLKS ((N_NODES + 255) / 256)  // 196

// ---------- fused: ve precompute (block 0) | dst histogram (blocks 1..) ----------
__global__ __launch_bounds__(256) void k_ve_hist(const float* __restrict__ We1, const float* __restrict__ atte1,
                                                 const float* __restrict__ We2, const float* __restrict__ atte2,
                                                 float* __restrict__ ve1, float* __restrict__ ve2,
                                                 const int* __restrict__ dst, int* __restrict__ cnt) {
    int b = blockIdx.x;
    int t = threadIdx.x;
    if (b == 0) {
        if (t < 32) {
            int k = t >> 1, h = t & 1;
            float s = 0.f;
            for (int c = 0; c < 64; ++c) s = fmaf(We1[k * 128 + h * 64 + c], atte1[h * 64 + c], s);
            ve1[k * 2 + h] = s;
        } else if (t < 48) {
            int k = t - 32;
            float s = 0.f;
            for (int c = 0; c < 64; ++c) s = fmaf(We2[k * 64 + c], atte2[c], s);
            ve2[k] = s;
        }
    } else {
        int e = (b - 1) * 256 + t;
        if (e < N_EDGES) atomicAdd(&cnt[dst[e]], 1);
    }
}

// ---------- conv1 node transform: h1 = x @ W1 (128->128) -> fp16, a_s1/a_d1 ----------
#define GRID1 1536
__global__ __launch_bounds__(128) void k_gemm1(const float* __restrict__ x, const float* __restrict__ W1,
                                               const float* __restrict__ atts, const float* __restrict__ attd,
                                               __half* __restrict__ h1, float* __restrict__ a_s,
                                               float* __restrict__ a_d) {
    __shared__ float xs[8][128];
    int j = threadIdx.x;
    int head = j >> 6;
    float wr[128];
#pragma unroll
    for (int k = 0; k < 128; ++k) wr[k] = W1[k * 128 + j];
    float asj = atts[j], adj = attd[j];
    for (int n0 = blockIdx.x * 8; n0 < N_NODES; n0 += GRID1 * 8) {
        __syncthreads();  // protect previous iteration's xs reads
        {
            const float4* src = (const float4*)(x + (size_t)n0 * 128);  // 256 float4 = 8 rows
            float4* dst = (float4*)&xs[0][0];
            dst[j] = src[j];
            dst[j + 128] = src[j + 128];
        }
        __syncthreads();
#pragma unroll 2
        for (int g = 0; g < 8; ++g) {
            int n = n0 + g;
            float a = 0.f;
#pragma unroll
            for (int k = 0; k < 128; ++k) a = fmaf(xs[g][k], wr[k], a);
            h1[(size_t)n * 128 + j] = __float2half(a);
            float ps = wred64(a * asj), pd = wred64(a * adj);
            if ((j & 63) == 0) {
                a_s[n * 2 + head] = ps;
                a_d[n * 2 + head] = pd;
            }
        }
    }
}

// ---------- conv2 node transform: h2 = h2in @ W2 (128->64) -> fp16, a_s2/a_d2 ----------
#define GRID2 3072
__global__ __launch_bounds__(64) void k_gemm2(const float* __restrict__ xin, const float* __restrict__ W,
                                              const float* __restrict__ atts, const float* __restrict__ attd,
                                              __half* __restrict__ h2, float* __restrict__ a_s,
                                              float* __restrict__ a_d) {
    __shared__ float xs[8][128];
    int j = threadIdx.x;
    float wr[128];
#pragma unroll
    for (int k = 0; k < 128; ++k) wr[k] = W[k * 64 + j];
    float asj = atts[j], adj = attd[j];
    for (int n0 = blockIdx.x * 8; n0 < N_NODES; n0 += GRID2 * 8) {
        __syncthreads();
        {
            const float4* src = (const float4*)(xin + (size_t)n0 * 128);  // 256 float4
            float4* dst = (float4*)&xs[0][0];
#pragma unroll
            for (int q = 0; q < 4; ++q) dst[j + 64 * q] = src[j + 64 * q];
        }
        __syncthreads();
#pragma unroll 2
        for (int g = 0; g < 8; ++g) {
            int n = n0 + g;
            float a = 0.f;
#pragma unroll
            for (int k = 0; k < 128; ++k) a = fmaf(xs[g][k], wr[k], a);
            h2[(size_t)n * 64 + j] = __float2half(a);
            float ps = wred64(a * asj), pd = wred64(a * adj);
            if (j == 0) {
                a_s[n] = ps;
                a_d[n] = pd;
            }
        }
    }
}

// ---------- fused: scan stage 1 | edge attn contributions + fp16 copy of ea ----------
__global__ __launch_bounds__(256) void k_scan1_ae(const int* __restrict__ cnt, int* __restrict__ bsum,
                                                  const float* __restrict__ ea, const float* __restrict__ ve1,
                                                  const float* __restrict__ ve2, float* __restrict__ ae1,
                                                  float* __restrict__ ae2, __half* __restrict__ ea_h) {
    __shared__ int ws[4];
    int b = blockIdx.x;
    int t = threadIdx.x;
    if (b < SCAN_BLKS) {
        int idx = b * 256 + t;
        int v = (idx < N_NODES) ? cnt[idx] : 0;
        int w = wredi64(v);
        if ((t & 63) == 0) ws[t >> 6] = w;
        __syncthreads();
        if (t == 0) bsum[b] = ws[0] + ws[1] + ws[2] + ws[3];
    } else {
        int e = (b - SCAN_BLKS) * 256 + t;
        if (e >= N_EDGES) return;
        float s0 = 0.f, s1 = 0.f, s2 = 0.f;
#pragma unroll
        for (int k = 0; k < 16; ++k) {
            float v = ea[e * 16 + k];
            ea_h[(size_t)e * 16 + k] = __float2half(v);
            s0 = fmaf(v, ve1[k * 2 + 0], s0);
            s1 = fmaf(v, ve1[k * 2 + 1], s1);
            s2 = fmaf(v, ve2[k], s2);
        }
        ae1[e * 2 + 0] = s0;
        ae1[e * 2 + 1] = s1;
        ae2[e] = s2;
    }
}

// ---------- scan stage 3 with self-scanned block offsets ----------
__global__ __launch_bounds__(256) void k_scan3b(const int* __restrict__ cnt, const int* __restrict__ bsum,
                                                int* __restrict__ rp, int* __restrict__ cursor) {
    __shared__ int sb[256];
    __shared__ int sh[256];
    int t = threadIdx.x;
    int bv = (t < SCAN_BLKS) ? bsum[t] : 0;
    sb[t] = bv;
    __syncthreads();
    for (int off = 1; off < 256; off <<= 1) {
        int u = (t >= off) ? sb[t - off] : 0;
        __syncthreads();
        sb[t] += u;
        __syncthreads();
    }
    int blkoff = (blockIdx.x > 0) ? sb[blockIdx.x - 1] : 0;
    int idx = blockIdx.x * 256 + t;
    int v = (idx < N_NODES) ? cnt[idx] : 0;
    sh[t] = v;
    __syncthreads();
    for (int off = 1; off < 256; off <<= 1) {
        int u = (t >= off) ? sh[t - off] : 0;
        __syncthreads();
        sh[t] += u;
        __syncthreads();
    }
    if (idx < N_NODES) {
        int excl = blkoff + sh[t] - v;
        rp[idx] = excl;
        cursor[idx] = excl;
        if (idx == N_NODES - 1) rp[N_NODES] = excl + v;
    }
}

// ---------- fused CSR fill + CSR-ordered edge tables ----------
__global__ void k_fillprep1(const int* __restrict__ dst, const int* __restrict__ src,
                            int* __restrict__ cursor, const float* __restrict__ as1,
                            const float* __restrict__ ae1, int* __restrict__ eord,
                            int* __restrict__ src_ord, float* __restrict__ zo1) {
    int e = blockIdx.x * blockDim.x + threadIdx.x;
    if (e >= N_EDGES) return;
    int p = atomicAdd(&cursor[dst[e]], 1);
    int s = src[e];
    eord[p] = e;
    src_ord[p] = s;
    zo1[p * 2 + 0] = as1[s * 2 + 0] + ae1[e * 2 + 0];
    zo1[p * 2 + 1] = as1[s * 2 + 1] + ae1[e * 2 + 1];
}

// ---------- conv1 fused softmax + gather + bias + ELU (barrier-free) ----------
template <int C, int H>
__global__ __launch_bounds__(C) void k_attn_gather(const int* __restrict__ rp, const int* __restrict__ src_ord,
                                                   const float* __restrict__ zo, const float* __restrict__ a_d,
                                                   const __half* __restrict__ hfeat, const float* __restrict__ bias,
                                                   float* __restrict__ outp) {
    int n = blockIdx.x;
    int tid = threadIdx.x;
    int beg = rp[n], end = rp[n + 1];
    const int hsel = (H == 2) ? (tid >> 6) : 0;
    float adn = a_d[n * H + hsel];
    float acc0 = 0.f, acc1 = 0.f, acc2 = 0.f, acc3 = 0.f;
    float sm0 = 0.f, sm1 = 0.f, sm2 = 0.f, sm3 = 0.f;
    int i = beg;
    for (; i + 3 < end; i += 4) {
        int s0 = src_ord[i], s1 = src_ord[i + 1], s2 = src_ord[i + 2], s3 = src_ord[i + 3];
        float z0 = zo[(size_t)i * H + hsel] + adn;
        float z1 = zo[(size_t)(i + 1) * H + hsel] + adn;
        float z2 = zo[(size_t)(i + 2) * H + hsel] + adn;
        float z3 = zo[(size_t)(i + 3) * H + hsel] + adn;
        z0 = z0 > 0.f ? z0 : NEG_SLOPE * z0;
        z1 = z1 > 0.f ? z1 : NEG_SLOPE * z1;
        z2 = z2 > 0.f ? z2 : NEG_SLOPE * z2;
        z3 = z3 > 0.f ? z3 : NEG_SLOPE * z3;
        float ex0 = __expf(z0), ex1 = __expf(z1), ex2 = __expf(z2), ex3 = __expf(z3);
        sm0 += ex0;
        sm1 += ex1;
        sm2 += ex2;
        sm3 += ex3;
        acc0 = fmaf(__half2float(hfeat[(size_t)s0 * C + tid]), ex0, acc0);
        acc1 = fmaf(__half2float(hfeat[(size_t)s1 * C + tid]), ex1, acc1);
        acc2 = fmaf(__half2float(hfeat[(size_t)s2 * C + tid]), ex2, acc2);
        acc3 = fmaf(__half2float(hfeat[(size_t)s3 * C + tid]), ex3, acc3);
    }
    for (; i < end; ++i) {
        int s0 = src_ord[i];
        float z0 = zo[(size_t)i * H + hsel] + adn;
        z0 = z0 > 0.f ? z0 : NEG_SLOPE * z0;
        float ex0 = __expf(z0);
        sm0 += ex0;
        acc0 = fmaf(__half2float(hfeat[(size_t)s0 * C + tid]), ex0, acc0);
    }
    float sm = (sm0 + sm1) + (sm2 + sm3);
    float acc = (acc0 + acc1) + (acc2 + acc3);
    float v = acc / (sm + 1e-16f) + bias[tid];
    outp[(size_t)n * C + tid] = v > 0.f ? v : expm1f(v);
}

// ---------- FUSED conv2 gather + softmax + ELU + classifier node-side (P1/P2) ----------
// 8 nodes per 64-thread block; Wc1 columns in 128 VGPRs (amortized over 8 nodes);
// logits computed inline (as2[s]+ae2[e]+ad2[n], all L2/L3-resident broadcasts);
// per node: barrier-free gather -> row in regs -> LDS stage -> two 64x64 dots -> fp16 P1/P2.
__global__ __launch_bounds__(64) void k_gather2_p12(const int* __restrict__ rp, const int* __restrict__ eord,
                                                    const int* __restrict__ src_ord, const float* __restrict__ as2,
                                                    const float* __restrict__ ae2, const float* __restrict__ ad2,
                                                    const __half* __restrict__ h2, const float* __restrict__ b2,
                                                    const float* __restrict__ Wc1, const float* __restrict__ bc1,
                                                    __half* __restrict__ P1, __half* __restrict__ P2) {
    __shared__ float xs[64];
    int j = threadIdx.x;
    float wr1[64], wr2[64];
#pragma unroll
    for (int k = 0; k < 64; ++k) {
        wr1[k] = Wc1[k * 64 + j];
        wr2[k] = Wc1[(64 + k) * 64 + j];
    }
    float bj = bc1[j];
    float b2j = b2[j];
    int n0 = blockIdx.x * 8;
    for (int g = 0; g < 8; ++g) {
        int n = n0 + g;
        int beg = rp[n], end = rp[n + 1];
        float adn = ad2[n];
        float acc0 = 0.f, acc1 = 0.f, acc2 = 0.f, acc3 = 0.f;
        float sm0 = 0.f, sm1 = 0.f, sm2 = 0.f, sm3 = 0.f;
        int i = beg;
        for (; i + 3 < end; i += 4) {
            int e0 = eord[i], e1 = eord[i + 1], e2 = eord[i + 2], e3 = eord[i + 3];
            int s0 = src_ord[i], s1 = src_ord[i + 1], s2 = src_ord[i + 2], s3 = src_ord[i + 3];
            float z0 = as2[s0] + ae2[e0] + adn;
            float z1 = as2[s1] + ae2[e1] + adn;
            float z2 = as2[s2] + ae2[e2] + adn;
            float z3 = as2[s3] + ae2[e3] + adn;
            z0 = z0 > 0.f ? z0 : NEG_SLOPE * z0;
            z1 = z1 > 0.f ? z1 : NEG_SLOPE * z1;
            z2 = z2 > 0.f ? z2 : NEG_SLOPE * z2;
            z3 = z3 > 0.f ? z3 : NEG_SLOPE * z3;
            float ex0 = __expf(z0), ex1 = __expf(z1), ex2 = __expf(z2), ex3 = __expf(z3);
            sm0 += ex0;
            sm1 += ex1;
            sm2 += ex2;
            sm3 += ex3;
            acc0 = fmaf(__half2float(h2[(size_t)s0 * 64 + j]), ex0, acc0);
            acc1 = fmaf(__half2float(h2[(size_t)s1 * 64 + j]), ex1, acc1);
            acc2 = fmaf(__half2float(h2[(size_t)s2 * 64 + j]), ex2, acc2);
            acc3 = fmaf(__half2float(h2[(size_t)s3 * 64 + j]), ex3, acc3);
        }
        for (; i < end; ++i) {
            int e0 = eord[i];
            int s0 = src_ord[i];
            float z0 = as2[s0] + ae2[e0] + adn;
            z0 = z0 > 0.f ? z0 : NEG_SLOPE * z0;
            float ex0 = __expf(z0);
            sm0 += ex0;
            acc0 = fmaf(__half2float(h2[(size_t)s0 * 64 + j]), ex0, acc0);
        }
        float sm = (sm0 + sm1) + (sm2 + sm3);
        float acc = (acc0 + acc1) + (acc2 + acc3);
        float v = acc / (sm + 1e-16f) + b2j;
        v = v > 0.f ? v : expm1f(v);  // ELU -> conv2 output row value for channel j
        __syncthreads();              // protect previous node's xs reads
        xs[j] = v;
        __syncthreads();
        float a1 = bj, a2v = 0.f;
#pragma unroll
        for (int k = 0; k < 64; ++k) {
            a1 = fmaf(xs[k], wr1[k], a1);
            a2v = fmaf(xs[k], wr2[k], a2v);
        }
        P1[(size_t)n * 64 + j] = __float2half(a1);
        P2[(size_t)n * 64 + j] = __float2half(a2v);
    }
}

// ---------- classifier edge-side: warp per dst segment, fp16 tables, ILP-4 ----------
__global__ __launch_bounds__(256) void k_final(const int* __restrict__ rp, const int* __restrict__ eord,
                                               const int* __restrict__ src_ord, const __half* __restrict__ ea,
                                               const __half* __restrict__ P1, const __half* __restrict__ P2,
                                               const float* __restrict__ Wc1, const float* __restrict__ Wc2,
                                               const float* __restrict__ bc2, float* __restrict__ out) {
    int tid = threadIdx.x;
    int lane = tid & 63;
    float wreg[16];
#pragma unroll
    for (int k = 0; k < 16; ++k) wreg[k] = Wc1[128 * 64 + k * 64 + lane];
    float w2 = Wc2[lane];
    float bc = bc2[0];
    int n = blockIdx.x * 4 + (tid >> 6);
    if (n >= N_NODES) return;
    int beg = __builtin_amdgcn_readfirstlane(rp[n]);
    int end = __builtin_amdgcn_readfirstlane(rp[n + 1]);
    if (beg >= end) return;
    float p2 = __half2float(P2[(size_t)n * 64 + lane]);
    int i = beg;
    for (; i + 3 < end; i += 4) {
        int e0 = __builtin_amdgcn_readfirstlane(eord[i]);
        int e1 = __builtin_amdgcn_readfirstlane(eord[i + 1]);
        int e2 = __builtin_amdgcn_readfirstlane(eord[i + 2]);
        int e3 = __builtin_amdgcn_readfirstlane(eord[i + 3]);
        int s0 = __builtin_amdgcn_readfirstlane(src_ord[i]);
        int s1 = __builtin_amdgcn_readfirstlane(src_ord[i + 1]);
        int s2 = __builtin_amdgcn_readfirstlane(src_ord[i + 2]);
        int s3 = __builtin_amdgcn_readfirstlane(src_ord[i + 3]);
        float h0 = p2 + __half2float(P1[(size_t)s0 * 64 + lane]);
        float h1 = p2 + __half2float(P1[(size_t)s1 * 64 + lane]);
        float h2 = p2 + __half2float(P1[(size_t)s2 * 64 + lane]);
        float h3 = p2 + __half2float(P1[(size_t)s3 * 64 + lane]);
        const __half* ea0 = ea + (size_t)e0 * 16;
        const __half* ea1 = ea + (size_t)e1 * 16;
        const __half* ea2 = ea + (size_t)e2 * 16;
        const __half* ea3 = ea + (size_t)e3 * 16;
#pragma unroll
        for (int k = 0; k < 16; ++k) {
            float wv = wreg[k];
            h0 = fmaf(__half2float(ea0[k]), wv, h0);
            h1 = fmaf(__half2float(ea1[k]), wv, h1);
            h2 = fmaf(__half2float(ea2[k]), wv, h2);
            h3 = fmaf(__half2float(ea3[k]), wv, h3);
        }
        h0 = fmaxf(h0, 0.f) * w2;
        h1 = fmaxf(h1, 0.f) * w2;
        h2 = fmaxf(h2, 0.f) * w2;
        h3 = fmaxf(h3, 0.f) * w2;
#pragma unroll
        for (int off = 32; off > 0; off >>= 1) {
            h0 += __shfl_xor(h0, off, 64);
            h1 += __shfl_xor(h1, off, 64);
            h2 += __shfl_xor(h2, off, 64);
            h3 += __shfl_xor(h3, off, 64);
        }
        if (lane == 0) {
            out[e0] = h0 + bc;
            out[e1] = h1 + bc;
            out[e2] = h2 + bc;
            out[e3] = h3 + bc;
        }
    }
    for (; i < end; ++i) {
        int e0 = __builtin_amdgcn_readfirstlane(eord[i]);
        int s0 = __builtin_amdgcn_readfirstlane(src_ord[i]);
        float h0 = p2 + __half2float(P1[(size_t)s0 * 64 + lane]);
        const __half* ea0 = ea + (size_t)e0 * 16;
#pragma unroll
        for (int k = 0; k < 16; ++k) h0 = fmaf(__half2float(ea0[k]), wreg[k], h0);
        h0 = fmaxf(h0, 0.f);
        float v = wred64(h0 * w2);
        if (lane == 0) out[e0] = v + bc;
    }
}

extern "C" void kernel_launch(void* const* d_in, const int* in_sizes, int n_in,
                              void* d_out, int out_size, void* d_ws, size_t ws_size,
                              hipStream_t stream) {
    const float* x     = (const float*)d_in[0];
    const int*   eidx  = (const int*)d_in[1];
    const float* ea    = (const float*)d_in[2];
    const float* W1    = (const float*)d_in[3];
    const float* atts1 = (const float*)d_in[4];
    const float* attd1 = (const float*)d_in[5];
    const float* We1   = (const float*)d_in[6];
    const float* atte1 = (const float*)d_in[7];
    const float* b1    = (const float*)d_in[8];
    const float* W2    = (const float*)d_in[9];
    const float* atts2 = (const float*)d_in[10];
    const float* attd2 = (const float*)d_in[11];
    const float* We2   = (const float*)d_in[12];
    const float* atte2 = (const float*)d_in[13];
    const float* b2    = (const float*)d_in[14];
    const float* Wc1   = (const float*)d_in[15];
    const float* bc1   = (const float*)d_in[16];
    const float* Wc2   = (const float*)d_in[17];
    const float* bc2   = (const float*)d_in[18];
    const int* srcp = eidx;
    const int* dstp = eidx + N_EDGES;
    float* out = (float*)d_out;

    char* w = (char*)d_ws;
    size_t off = 0;
    auto alloc = [&](size_t bytes) -> void* {
        void* p = w + off;
        off += (bytes + 255) & ~size_t(255);
        return p;
    };

    __half* h1h  = (__half*)alloc(N_NODES * 128 * sizeof(__half));  // conv1 features; later h2
    float* as1  = (float*)alloc(N_NODES * 2 * sizeof(float));
    float* ad1  = (float*)alloc(N_NODES * 2 * sizeof(float));
    float* ae1  = (float*)alloc(N_EDGES * 2 * sizeof(float));
    float* ae2  = (float*)alloc(N_EDGES * sizeof(float));
    float* as2  = (float*)alloc(N_NODES * sizeof(float));
    float* ad2  = (float*)alloc(N_NODES * sizeof(float));
    float* ve1  = (float*)alloc(32 * sizeof(float));
    float* ve2  = (float*)alloc(16 * sizeof(float));
    int*   rp      = (int*)alloc((N_NODES + 1) * sizeof(int));
    int*   eord    = (int*)alloc(N_EDGES * sizeof(int));
    int*   cursor  = (int*)alloc(N_NODES * sizeof(int));
    int*   src_ord = (int*)alloc(N_EDGES * sizeof(int));
    float* zo1     = (float*)alloc(N_EDGES * 2 * sizeof(float));
    float* out1    = (float*)alloc(N_NODES * 128 * sizeof(float));
    __half* ea_h   = (__half*)alloc((size_t)N_EDGES * 16 * sizeof(__half));
    int*   bsum    = (int*)alloc(SCAN_BLKS * sizeof(int));

    // aliases (lifetime-disjoint)
    __half* h2h = h1h;                        // [N,64] fp16: gemm2 writes after h1's last read (gather1)
    __half* P1h = (__half*)out1;              // [N,64] fp16: fused kernel writes after out1's last read (gemm2)
    __half* P2h = P1h + (size_t)N_NODES * 64; // still inside out1's 25.6MB region (needs 12.8MB total)

    // zeroed-every-call region
    char* zstart = w + off;
    int* cnt = (int*)alloc(N_NODES * sizeof(int));
    size_t zbytes = (size_t)((w + off) - zstart);
    hipMemsetAsync(zstart, 0, zbytes, stream);

    const int EB = (N_EDGES + 255) / 256;  // 3125

    // L1: ve | dst histogram
    k_ve_hist<<<1 + EB, 256, 0, stream>>>(We1, atte1, We2, atte2, ve1, ve2, dstp, cnt);
    // L2: conv1 node GEMM (fp16 output)
    k_gemm1<<<GRID1, 128, 0, stream>>>(x, W1, atts1, attd1, h1h, as1, ad1);
    // L3: scan stage 1 | edge attn contributions + ea fp16 copy
    k_scan1_ae<<<SCAN_BLKS + EB, 256, 0, stream>>>(cnt, bsum, ea, ve1, ve2, ae1, ae2, ea_h);
    // L4: scan stage 3 -> rp, cursor
    k_scan3b<<<SCAN_BLKS, 256, 0, stream>>>(cnt, bsum, rp, cursor);
    // L5: CSR fill + CSR-ordered tables (eord, src_ord, zo1)
    k_fillprep1<<<EB, 256, 0, stream>>>(dstp, srcp, cursor, as1, ae1, eord, src_ord, zo1);
    // L6: conv1 fused softmax+aggregate+bias+ELU (fp16 gather)
    k_attn_gather<128, 2><<<N_NODES, 128, 0, stream>>>(rp, src_ord, zo1, ad1, h1h, b1, out1);
    // L7: conv2 node GEMM (fp16 output)
    k_gemm2<<<GRID2, 64, 0, stream>>>(out1, W2, atts2, attd2, h2h, as2, ad2);
    // L8: FUSED conv2 gather+softmax+ELU + classifier node-side -> P1/P2 (fp16)
    k_gather2_p12<<<N_NODES / 8, 64, 0, stream>>>(rp, eord, src_ord, as2, ae2, ad2, h2h, b2, Wc1, bc1, P1h, P2h);
    // L9: classifier edge-side
    k_final<<<(N_NODES + 3) / 4, 256, 0, stream>>>(rp, eord, src_ord, ea_h, P1h, P2h, Wc1, Wc2, bc2, out);
}

// Round 18
// 416.967 us; speedup vs baseline: 1.0679x; 1.0679x over previous
//
#include <hip/hip_runtime.h>
#include <hip/hip_fp16.h>
#include <math.h>

#define N_NODES 50000
#define N_EDGES 800000
#define NEG_SLOPE 0.2f

// ---------- helpers ----------
__device__ __forceinline__ float wred64(float v) {
#pragma unroll
    for (int off = 32; off > 0; off >>= 1) v += __shfl_xor(v, off, 64);
    return v;
}
__device__ __forceinline__ int wredi64(int v) {
#pragma unroll
    for (int off = 32; off > 0; off >>= 1) v += __shfl_xor(v, off, 64);
    return v;
}

#define SCAN_BLKS ((N_NODES + 255) / 256)  // 196

// ---------- fused: ve precompute (block 0) | dst histogram (blocks 1..) ----------
__global__ __launch_bounds__(256) void k_ve_hist(const float* __restrict__ We1, const float* __restrict__ atte1,
                                                 const float* __restrict__ We2, const float* __restrict__ atte2,
                                                 float* __restrict__ ve1, float* __restrict__ ve2,
                                                 const int* __restrict__ dst, int* __restrict__ cnt) {
    int b = blockIdx.x;
    int t = threadIdx.x;
    if (b == 0) {
        if (t < 32) {
            int k = t >> 1, h = t & 1;
            float s = 0.f;
            for (int c = 0; c < 64; ++c) s = fmaf(We1[k * 128 + h * 64 + c], atte1[h * 64 + c], s);
            ve1[k * 2 + h] = s;
        } else if (t < 48) {
            int k = t - 32;
            float s = 0.f;
            for (int c = 0; c < 64; ++c) s = fmaf(We2[k * 64 + c], atte2[c], s);
            ve2[k] = s;
        }
    } else {
        int e = (b - 1) * 256 + t;
        if (e < N_EDGES) atomicAdd(&cnt[dst[e]], 1);
    }
}

// ---------- conv1 node transform: h1 = x @ W1 (128->128) -> fp16, a_s1/a_d1 ----------
#define GRID1 1536
__global__ __launch_bounds__(128) void k_gemm1(const float* __restrict__ x, const float* __restrict__ W1,
                                               const float* __restrict__ atts, const float* __restrict__ attd,
                                               __half* __restrict__ h1, float* __restrict__ a_s,
                                               float* __restrict__ a_d) {
    __shared__ float xs[8][128];
    int j = threadIdx.x;
    int head = j >> 6;
    float wr[128];
#pragma unroll
    for (int k = 0; k < 128; ++k) wr[k] = W1[k * 128 + j];
    float asj = atts[j], adj = attd[j];
    for (int n0 = blockIdx.x * 8; n0 < N_NODES; n0 += GRID1 * 8) {
        __syncthreads();  // protect previous iteration's xs reads
        {
            const float4* src = (const float4*)(x + (size_t)n0 * 128);  // 256 float4 = 8 rows
            float4* dst = (float4*)&xs[0][0];
            dst[j] = src[j];
            dst[j + 128] = src[j + 128];
        }
        __syncthreads();
#pragma unroll 2
        for (int g = 0; g < 8; ++g) {
            int n = n0 + g;
            float a = 0.f;
#pragma unroll
            for (int k = 0; k < 128; ++k) a = fmaf(xs[g][k], wr[k], a);
            h1[(size_t)n * 128 + j] = __float2half(a);
            float ps = wred64(a * asj), pd = wred64(a * adj);
            if ((j & 63) == 0) {
                a_s[n * 2 + head] = ps;
                a_d[n * 2 + head] = pd;
            }
        }
    }
}

// ---------- conv2 node transform: h2 = h2in @ W2 (128->64) -> fp16, a_s2/a_d2 ----------
#define GRID2 3072
__global__ __launch_bounds__(64) void k_gemm2(const float* __restrict__ xin, const float* __restrict__ W,
                                              const float* __restrict__ atts, const float* __restrict__ attd,
                                              __half* __restrict__ h2, float* __restrict__ a_s,
                                              float* __restrict__ a_d) {
    __shared__ float xs[8][128];
    int j = threadIdx.x;
    float wr[128];
#pragma unroll
    for (int k = 0; k < 128; ++k) wr[k] = W[k * 64 + j];
    float asj = atts[j], adj = attd[j];
    for (int n0 = blockIdx.x * 8; n0 < N_NODES; n0 += GRID2 * 8) {
        __syncthreads();
        {
            const float4* src = (const float4*)(xin + (size_t)n0 * 128);  // 256 float4
            float4* dst = (float4*)&xs[0][0];
#pragma unroll
            for (int q = 0; q < 4; ++q) dst[j + 64 * q] = src[j + 64 * q];
        }
        __syncthreads();
#pragma unroll 2
        for (int g = 0; g < 8; ++g) {
            int n = n0 + g;
            float a = 0.f;
#pragma unroll
            for (int k = 0; k < 128; ++k) a = fmaf(xs[g][k], wr[k], a);
            h2[(size_t)n * 64 + j] = __float2half(a);
            float ps = wred64(a * asj), pd = wred64(a * adj);
            if (j == 0) {
                a_s[n] = ps;
                a_d[n] = pd;
            }
        }
    }
}

// ---------- classifier node-side: P1 = hf@Wc1[0:64]+bc1, P2 = hf@Wc1[64:128] -> fp16 ----------
__global__ __launch_bounds__(64) void k_p12(const float* __restrict__ hf, const float* __restrict__ Wc1,
                                            const float* __restrict__ bc1, __half* __restrict__ P1,
                                            __half* __restrict__ P2) {
    __shared__ float xs[8][64];
    int j = threadIdx.x;
    float wr1[64], wr2[64];
#pragma unroll
    for (int k = 0; k < 64; ++k) {
        wr1[k] = Wc1[k * 64 + j];
        wr2[k] = Wc1[(64 + k) * 64 + j];
    }
    float bj = bc1[j];
    for (int n0 = blockIdx.x * 8; n0 < N_NODES; n0 += GRID2 * 8) {
        __syncthreads();
        {
            const float4* src = (const float4*)(hf + (size_t)n0 * 64);  // 128 float4 = 8 rows
            float4* dst = (float4*)&xs[0][0];
            dst[j] = src[j];
            dst[j + 64] = src[j + 64];
        }
        __syncthreads();
#pragma unroll 2
        for (int g = 0; g < 8; ++g) {
            int n = n0 + g;
            float a1 = bj, a2 = 0.f;
#pragma unroll
            for (int k = 0; k < 64; ++k) {
                a1 = fmaf(xs[g][k], wr1[k], a1);
                a2 = fmaf(xs[g][k], wr2[k], a2);
            }
            P1[(size_t)n * 64 + j] = __float2half(a1);
            P2[(size_t)n * 64 + j] = __float2half(a2);
        }
    }
}

// ---------- fused: scan stage 1 | edge attn contributions + fp16 copy of ea ----------
__global__ __launch_bounds__(256) void k_scan1_ae(const int* __restrict__ cnt, int* __restrict__ bsum,
                                                  const float* __restrict__ ea, const float* __restrict__ ve1,
                                                  const float* __restrict__ ve2, float* __restrict__ ae1,
                                                  float* __restrict__ ae2, __half* __restrict__ ea_h) {
    __shared__ int ws[4];
    int b = blockIdx.x;
    int t = threadIdx.x;
    if (b < SCAN_BLKS) {
        int idx = b * 256 + t;
        int v = (idx < N_NODES) ? cnt[idx] : 0;
        int w = wredi64(v);
        if ((t & 63) == 0) ws[t >> 6] = w;
        __syncthreads();
        if (t == 0) bsum[b] = ws[0] + ws[1] + ws[2] + ws[3];
    } else {
        int e = (b - SCAN_BLKS) * 256 + t;
        if (e >= N_EDGES) return;
        float s0 = 0.f, s1 = 0.f, s2 = 0.f;
#pragma unroll
        for (int k = 0; k < 16; ++k) {
            float v = ea[e * 16 + k];
            ea_h[(size_t)e * 16 + k] = __float2half(v);
            s0 = fmaf(v, ve1[k * 2 + 0], s0);
            s1 = fmaf(v, ve1[k * 2 + 1], s1);
            s2 = fmaf(v, ve2[k], s2);
        }
        ae1[e * 2 + 0] = s0;
        ae1[e * 2 + 1] = s1;
        ae2[e] = s2;
    }
}

// ---------- scan stage 3 with self-scanned block offsets ----------
__global__ __launch_bounds__(256) void k_scan3b(const int* __restrict__ cnt, const int* __restrict__ bsum,
                                                int* __restrict__ rp, int* __restrict__ cursor) {
    __shared__ int sb[256];
    __shared__ int sh[256];
    int t = threadIdx.x;
    int bv = (t < SCAN_BLKS) ? bsum[t] : 0;
    sb[t] = bv;
    __syncthreads();
    for (int off = 1; off < 256; off <<= 1) {
        int u = (t >= off) ? sb[t - off] : 0;
        __syncthreads();
        sb[t] += u;
        __syncthreads();
    }
    int blkoff = (blockIdx.x > 0) ? sb[blockIdx.x - 1] : 0;
    int idx = blockIdx.x * 256 + t;
    int v = (idx < N_NODES) ? cnt[idx] : 0;
    sh[t] = v;
    __syncthreads();
    for (int off = 1; off < 256; off <<= 1) {
        int u = (t >= off) ? sh[t - off] : 0;
        __syncthreads();
        sh[t] += u;
        __syncthreads();
    }
    if (idx < N_NODES) {
        int excl = blkoff + sh[t] - v;
        rp[idx] = excl;
        cursor[idx] = excl;
        if (idx == N_NODES - 1) rp[N_NODES] = excl + v;
    }
}

// ---------- fused CSR fill + CSR-ordered edge tables ----------
__global__ void k_fillprep1(const int* __restrict__ dst, const int* __restrict__ src,
                            int* __restrict__ cursor, const float* __restrict__ as1,
                            const float* __restrict__ ae1, int* __restrict__ eord,
                            int* __restrict__ src_ord, float* __restrict__ zo1) {
    int e = blockIdx.x * blockDim.x + threadIdx.x;
    if (e >= N_EDGES) return;
    int p = atomicAdd(&cursor[dst[e]], 1);
    int s = src[e];
    eord[p] = e;
    src_ord[p] = s;
    zo1[p * 2 + 0] = as1[s * 2 + 0] + ae1[e * 2 + 0];
    zo1[p * 2 + 1] = as1[s * 2 + 1] + ae1[e * 2 + 1];
}

// ---------- conv1 fused softmax + gather + bias + ELU (barrier-free) ----------
template <int C, int H>
__global__ __launch_bounds__(C) void k_attn_gather(const int* __restrict__ rp, const int* __restrict__ src_ord,
                                                   const float* __restrict__ zo, const float* __restrict__ a_d,
                                                   const __half* __restrict__ hfeat, const float* __restrict__ bias,
                                                   float* __restrict__ outp) {
    int n = blockIdx.x;
    int tid = threadIdx.x;
    int beg = rp[n], end = rp[n + 1];
    const int hsel = (H == 2) ? (tid >> 6) : 0;
    float adn = a_d[n * H + hsel];
    float acc0 = 0.f, acc1 = 0.f, acc2 = 0.f, acc3 = 0.f;
    float sm0 = 0.f, sm1 = 0.f, sm2 = 0.f, sm3 = 0.f;
    int i = beg;
    for (; i + 3 < end; i += 4) {
        int s0 = src_ord[i], s1 = src_ord[i + 1], s2 = src_ord[i + 2], s3 = src_ord[i + 3];
        float z0 = zo[(size_t)i * H + hsel] + adn;
        float z1 = zo[(size_t)(i + 1) * H + hsel] + adn;
        float z2 = zo[(size_t)(i + 2) * H + hsel] + adn;
        float z3 = zo[(size_t)(i + 3) * H + hsel] + adn;
        z0 = z0 > 0.f ? z0 : NEG_SLOPE * z0;
        z1 = z1 > 0.f ? z1 : NEG_SLOPE * z1;
        z2 = z2 > 0.f ? z2 : NEG_SLOPE * z2;
        z3 = z3 > 0.f ? z3 : NEG_SLOPE * z3;
        float ex0 = __expf(z0), ex1 = __expf(z1), ex2 = __expf(z2), ex3 = __expf(z3);
        sm0 += ex0;
        sm1 += ex1;
        sm2 += ex2;
        sm3 += ex3;
        acc0 = fmaf(__half2float(hfeat[(size_t)s0 * C + tid]), ex0, acc0);
        acc1 = fmaf(__half2float(hfeat[(size_t)s1 * C + tid]), ex1, acc1);
        acc2 = fmaf(__half2float(hfeat[(size_t)s2 * C + tid]), ex2, acc2);
        acc3 = fmaf(__half2float(hfeat[(size_t)s3 * C + tid]), ex3, acc3);
    }
    for (; i < end; ++i) {
        int s0 = src_ord[i];
        float z0 = zo[(size_t)i * H + hsel] + adn;
        z0 = z0 > 0.f ? z0 : NEG_SLOPE * z0;
        float ex0 = __expf(z0);
        sm0 += ex0;
        acc0 = fmaf(__half2float(hfeat[(size_t)s0 * C + tid]), ex0, acc0);
    }
    float sm = (sm0 + sm1) + (sm2 + sm3);
    float acc = (acc0 + acc1) + (acc2 + acc3);
    float v = acc / (sm + 1e-16f) + bias[tid];
    outp[(size_t)n * C + tid] = v > 0.f ? v : expm1f(v);
}

// ---------- conv2 gather with INLINE logits (replaces prep2 + gather<64,1>) ----------
// Barrier-free, 1 block per dst node, 64 threads; z = as2[s] + ae2[e] + ad2[n]
// (as2/ad2 0.2MB, ae2 3.2MB: L2-resident broadcasts; eord/src_ord contiguous streams).
__global__ __launch_bounds__(64) void k_attn_gather2(const int* __restrict__ rp, const int* __restrict__ eord,
                                                     const int* __restrict__ src_ord, const float* __restrict__ as2,
                                                     const float* __restrict__ ae2, const float* __restrict__ ad2,
                                                     const __half* __restrict__ hfeat, const float* __restrict__ bias,
                                                     float* __restrict__ outp) {
    int n = blockIdx.x;
    int tid = threadIdx.x;
    int beg = rp[n], end = rp[n + 1];
    float adn = ad2[n];
    float acc0 = 0.f, acc1 = 0.f, acc2 = 0.f, acc3 = 0.f;
    float sm0 = 0.f, sm1 = 0.f, sm2 = 0.f, sm3 = 0.f;
    int i = beg;
    for (; i + 3 < end; i += 4) {
        int e0 = eord[i], e1 = eord[i + 1], e2 = eord[i + 2], e3 = eord[i + 3];
        int s0 = src_ord[i], s1 = src_ord[i + 1], s2 = src_ord[i + 2], s3 = src_ord[i + 3];
        float z0 = as2[s0] + ae2[e0] + adn;
        float z1 = as2[s1] + ae2[e1] + adn;
        float z2 = as2[s2] + ae2[e2] + adn;
        float z3 = as2[s3] + ae2[e3] + adn;
        z0 = z0 > 0.f ? z0 : NEG_SLOPE * z0;
        z1 = z1 > 0.f ? z1 : NEG_SLOPE * z1;
        z2 = z2 > 0.f ? z2 : NEG_SLOPE * z2;
        z3 = z3 > 0.f ? z3 : NEG_SLOPE * z3;
        float ex0 = __expf(z0), ex1 = __expf(z1), ex2 = __expf(z2), ex3 = __expf(z3);
        sm0 += ex0;
        sm1 += ex1;
        sm2 += ex2;
        sm3 += ex3;
        acc0 = fmaf(__half2float(hfeat[(size_t)s0 * 64 + tid]), ex0, acc0);
        acc1 = fmaf(__half2float(hfeat[(size_t)s1 * 64 + tid]), ex1, acc1);
        acc2 = fmaf(__half2float(hfeat[(size_t)s2 * 64 + tid]), ex2, acc2);
        acc3 = fmaf(__half2float(hfeat[(size_t)s3 * 64 + tid]), ex3, acc3);
    }
    for (; i < end; ++i) {
        int e0 = eord[i];
        int s0 = src_ord[i];
        float z0 = as2[s0] + ae2[e0] + adn;
        z0 = z0 > 0.f ? z0 : NEG_SLOPE * z0;
        float ex0 = __expf(z0);
        sm0 += ex0;
        acc0 = fmaf(__half2float(hfeat[(size_t)s0 * 64 + tid]), ex0, acc0);
    }
    float sm = (sm0 + sm1) + (sm2 + sm3);
    float acc = (acc0 + acc1) + (acc2 + acc3);
    float v = acc / (sm + 1e-16f) + bias[tid];
    outp[(size_t)n * 64 + tid] = v > 0.f ? v : expm1f(v);
}

// ---------- classifier edge-side: warp per dst segment, fp16 tables, ILP-4 ----------
__global__ __launch_bounds__(256) void k_final(const int* __restrict__ rp, const int* __restrict__ eord,
                                               const int* __restrict__ src_ord, const __half* __restrict__ ea,
                                               const __half* __restrict__ P1, const __half* __restrict__ P2,
                                               const float* __restrict__ Wc1, const float* __restrict__ Wc2,
                                               const float* __restrict__ bc2, float* __restrict__ out) {
    int tid = threadIdx.x;
    int lane = tid & 63;
    float wreg[16];
#pragma unroll
    for (int k = 0; k < 16; ++k) wreg[k] = Wc1[128 * 64 + k * 64 + lane];
    float w2 = Wc2[lane];
    float bc = bc2[0];
    int n = blockIdx.x * 4 + (tid >> 6);
    if (n >= N_NODES) return;
    int beg = __builtin_amdgcn_readfirstlane(rp[n]);
    int end = __builtin_amdgcn_readfirstlane(rp[n + 1]);
    if (beg >= end) return;
    float p2 = __half2float(P2[(size_t)n * 64 + lane]);
    int i = beg;
    for (; i + 3 < end; i += 4) {
        int e0 = __builtin_amdgcn_readfirstlane(eord[i]);
        int e1 = __builtin_amdgcn_readfirstlane(eord[i + 1]);
        int e2 = __builtin_amdgcn_readfirstlane(eord[i + 2]);
        int e3 = __builtin_amdgcn_readfirstlane(eord[i + 3]);
        int s0 = __builtin_amdgcn_readfirstlane(src_ord[i]);
        int s1 = __builtin_amdgcn_readfirstlane(src_ord[i + 1]);
        int s2 = __builtin_amdgcn_readfirstlane(src_ord[i + 2]);
        int s3 = __builtin_amdgcn_readfirstlane(src_ord[i + 3]);
        float h0 = p2 + __half2float(P1[(size_t)s0 * 64 + lane]);
        float h1 = p2 + __half2float(P1[(size_t)s1 * 64 + lane]);
        float h2 = p2 + __half2float(P1[(size_t)s2 * 64 + lane]);
        float h3 = p2 + __half2float(P1[(size_t)s3 * 64 + lane]);
        const __half* ea0 = ea + (size_t)e0 * 16;
        const __half* ea1 = ea + (size_t)e1 * 16;
        const __half* ea2 = ea + (size_t)e2 * 16;
        const __half* ea3 = ea + (size_t)e3 * 16;
#pragma unroll
        for (int k = 0; k < 16; ++k) {
            float wv = wreg[k];
            h0 = fmaf(__half2float(ea0[k]), wv, h0);
            h1 = fmaf(__half2float(ea1[k]), wv, h1);
            h2 = fmaf(__half2float(ea2[k]), wv, h2);
            h3 = fmaf(__half2float(ea3[k]), wv, h3);
        }
        h0 = fmaxf(h0, 0.f) * w2;
        h1 = fmaxf(h1, 0.f) * w2;
        h2 = fmaxf(h2, 0.f) * w2;
        h3 = fmaxf(h3, 0.f) * w2;
#pragma unroll
        for (int off = 32; off > 0; off >>= 1) {
            h0 += __shfl_xor(h0, off, 64);
            h1 += __shfl_xor(h1, off, 64);
            h2 += __shfl_xor(h2, off, 64);
            h3 += __shfl_xor(h3, off, 64);
        }
        if (lane == 0) {
            out[e0] = h0 + bc;
            out[e1] = h1 + bc;
            out[e2] = h2 + bc;
            out[e3] = h3 + bc;
        }
    }
    for (; i < end; ++i) {
        int e0 = __builtin_amdgcn_readfirstlane(eord[i]);
        int s0 = __builtin_amdgcn_readfirstlane(src_ord[i]);
        float h0 = p2 + __half2float(P1[(size_t)s0 * 64 + lane]);
        const __half* ea0 = ea + (size_t)e0 * 16;
#pragma unroll
        for (int k = 0; k < 16; ++k) h0 = fmaf(__half2float(ea0[k]), wreg[k], h0);
        h0 = fmaxf(h0, 0.f);
        float v = wred64(h0 * w2);
        if (lane == 0) out[e0] = v + bc;
    }
}

extern "C" void kernel_launch(void* const* d_in, const int* in_sizes, int n_in,
                              void* d_out, int out_size, void* d_ws, size_t ws_size,
                              hipStream_t stream) {
    const float* x     = (const float*)d_in[0];
    const int*   eidx  = (const int*)d_in[1];
    const float* ea    = (const float*)d_in[2];
    const float* W1    = (const float*)d_in[3];
    const float* atts1 = (const float*)d_in[4];
    const float* attd1 = (const float*)d_in[5];
    const float* We1   = (const float*)d_in[6];
    const float* atte1 = (const float*)d_in[7];
    const float* b1    = (const float*)d_in[8];
    const float* W2    = (const float*)d_in[9];
    const float* atts2 = (const float*)d_in[10];
    const float* attd2 = (const float*)d_in[11];
    const float* We2   = (const float*)d_in[12];
    const float* atte2 = (const float*)d_in[13];
    const float* b2    = (const float*)d_in[14];
    const float* Wc1   = (const float*)d_in[15];
    const float* bc1   = (const float*)d_in[16];
    const float* Wc2   = (const float*)d_in[17];
    const float* bc2   = (const float*)d_in[18];
    const int* srcp = eidx;
    const int* dstp = eidx + N_EDGES;
    float* out = (float*)d_out;

    char* w = (char*)d_ws;
    size_t off = 0;
    auto alloc = [&](size_t bytes) -> void* {
        void* p = w + off;
        off += (bytes + 255) & ~size_t(255);
        return p;
    };

    __half* h1h  = (__half*)alloc(N_NODES * 128 * sizeof(__half));  // conv1 features; later h2/P1/P2
    float* as1  = (float*)alloc(N_NODES * 2 * sizeof(float));
    float* ad1  = (float*)alloc(N_NODES * 2 * sizeof(float));
    float* ae1  = (float*)alloc(N_EDGES * 2 * sizeof(float));
    float* ae2  = (float*)alloc(N_EDGES * sizeof(float));
    float* as2  = (float*)alloc(N_NODES * sizeof(float));
    float* ad2  = (float*)alloc(N_NODES * sizeof(float));
    float* ve1  = (float*)alloc(32 * sizeof(float));
    float* ve2  = (float*)alloc(16 * sizeof(float));
    int*   rp      = (int*)alloc((N_NODES + 1) * sizeof(int));
    int*   eord    = (int*)alloc(N_EDGES * sizeof(int));
    int*   cursor  = (int*)alloc(N_NODES * sizeof(int));
    int*   src_ord = (int*)alloc(N_EDGES * sizeof(int));
    float* zo1     = (float*)alloc(N_EDGES * 2 * sizeof(float));
    float* out1    = (float*)alloc(N_NODES * 128 * sizeof(float));
    __half* ea_h   = (__half*)alloc((size_t)N_EDGES * 16 * sizeof(__half));
    int*   bsum    = (int*)alloc(SCAN_BLKS * sizeof(int));

    // aliases (lifetime-disjoint) — identical discipline to the 394µs R16 kernel
    __half* h2h = h1h;                 // [N,64] fp16: gemm2 writes after h1's last read (gather1)
    __half* P1h = h1h;                 // [N,64] fp16: p12 writes after h2's last read (gather2)
    __half* P2h = h1h + (size_t)N_NODES * 64;
    float* out2 = out1;                // [N,64]: gather2 writes after out1's last read (gemm2)

    // zeroed-every-call region
    char* zstart = w + off;
    int* cnt = (int*)alloc(N_NODES * sizeof(int));
    size_t zbytes = (size_t)((w + off) - zstart);
    hipMemsetAsync(zstart, 0, zbytes, stream);

    const int EB = (N_EDGES + 255) / 256;  // 3125

    // L1: ve | dst histogram
    k_ve_hist<<<1 + EB, 256, 0, stream>>>(We1, atte1, We2, atte2, ve1, ve2, dstp, cnt);
    // L2: conv1 node GEMM (fp16 output)
    k_gemm1<<<GRID1, 128, 0, stream>>>(x, W1, atts1, attd1, h1h, as1, ad1);
    // L3: scan stage 1 | edge attn contributions + ea fp16 copy
    k_scan1_ae<<<SCAN_BLKS + EB, 256, 0, stream>>>(cnt, bsum, ea, ve1, ve2, ae1, ae2, ea_h);
    // L4: scan stage 3 -> rp, cursor
    k_scan3b<<<SCAN_BLKS, 256, 0, stream>>>(cnt, bsum, rp, cursor);
    // L5: CSR fill + CSR-ordered tables (eord, src_ord, zo1)
    k_fillprep1<<<EB, 256, 0, stream>>>(dstp, srcp, cursor, as1, ae1, eord, src_ord, zo1);
    // L6: conv1 fused softmax+aggregate+bias+ELU (fp16 gather)
    k_attn_gather<128, 2><<<N_NODES, 128, 0, stream>>>(rp, src_ord, zo1, ad1, h1h, b1, out1);
    // L7: conv2 node GEMM (fp16 output)
    k_gemm2<<<GRID2, 64, 0, stream>>>(out1, W2, atts2, attd2, h2h, as2, ad2);
    // L8: conv2 gather with inline logits (prep2 deleted)
    k_attn_gather2<<<N_NODES, 64, 0, stream>>>(rp, eord, src_ord, as2, ae2, ad2, h2h, b2, out2);
    // L9: classifier node-side (fp16 tables)
    k_p12<<<GRID2, 64, 0, stream>>>(out2, Wc1, bc1, P1h, P2h);
    // L10: classifier edge-side
    k_final<<<(N_NODES + 3) / 4, 256, 0, stream>>>(rp, eord, src_ord, ea_h, P1h, P2h, Wc1, Wc2, bc2, out);
}

// Round 19
// 392.965 us; speedup vs baseline: 1.1331x; 1.0611x over previous
//
#include <hip/hip_runtime.h>
#include <hip/hip_fp16.h>
#include <math.h>

#define N_NODES 50000
#define N_EDGES 800000
#define NEG_SLOPE 0.2f

// ---------- helpers ----------
__device__ __forceinline__ float wred64(float v) {
#pragma unroll
    for (int off = 32; off > 0; off >>= 1) v += __shfl_xor(v, off, 64);
    return v;
}
__device__ __forceinline__ int wredi64(int v) {
#pragma unroll
    for (int off = 32; off > 0; off >>= 1) v += __shfl_xor(v, off, 64);
    return v;
}

#define SCAN_BLKS ((N_NODES + 255) / 256)  // 196

// ---------- fused: ve precompute (block 0) | dst histogram (blocks 1..) ----------
__global__ __launch_bounds__(256) void k_ve_hist(const float* __restrict__ We1, const float* __restrict__ atte1,
                                                 const float* __restrict__ We2, const float* __restrict__ atte2,
                                                 float* __restrict__ ve1, float* __restrict__ ve2,
                                                 const int* __restrict__ dst, int* __restrict__ cnt) {
    int b = blockIdx.x;
    int t = threadIdx.x;
    if (b == 0) {
        if (t < 32) {
            int k = t >> 1, h = t & 1;
            float s = 0.f;
            for (int c = 0; c < 64; ++c) s = fmaf(We1[k * 128 + h * 64 + c], atte1[h * 64 + c], s);
            ve1[k * 2 + h] = s;
        } else if (t < 48) {
            int k = t - 32;
            float s = 0.f;
            for (int c = 0; c < 64; ++c) s = fmaf(We2[k * 64 + c], atte2[c], s);
            ve2[k] = s;
        }
    } else {
        int e = (b - 1) * 256 + t;
        if (e < N_EDGES) atomicAdd(&cnt[dst[e]], 1);
    }
}

// ---------- conv1 node transform: h1 = x @ W1 (128->128) -> fp16, a_s1/a_d1 ----------
#define GRID1 1536
__global__ __launch_bounds__(128) void k_gemm1(const float* __restrict__ x, const float* __restrict__ W1,
                                               const float* __restrict__ atts, const float* __restrict__ attd,
                                               __half* __restrict__ h1, float* __restrict__ a_s,
                                               float* __restrict__ a_d) {
    __shared__ float xs[8][128];
    int j = threadIdx.x;
    int head = j >> 6;
    float wr[128];
#pragma unroll
    for (int k = 0; k < 128; ++k) wr[k] = W1[k * 128 + j];
    float asj = atts[j], adj = attd[j];
    for (int n0 = blockIdx.x * 8; n0 < N_NODES; n0 += GRID1 * 8) {
        __syncthreads();  // protect previous iteration's xs reads
        {
            const float4* src = (const float4*)(x + (size_t)n0 * 128);  // 256 float4 = 8 rows
            float4* dst = (float4*)&xs[0][0];
            dst[j] = src[j];
            dst[j + 128] = src[j + 128];
        }
        __syncthreads();
#pragma unroll 2
        for (int g = 0; g < 8; ++g) {
            int n = n0 + g;
            float a = 0.f;
#pragma unroll
            for (int k = 0; k < 128; ++k) a = fmaf(xs[g][k], wr[k], a);
            h1[(size_t)n * 128 + j] = __float2half(a);
            float ps = wred64(a * asj), pd = wred64(a * adj);
            if ((j & 63) == 0) {
                a_s[n * 2 + head] = ps;
                a_d[n * 2 + head] = pd;
            }
        }
    }
}

// ---------- conv2 node transform: h2 = h2in @ W2 (128->64) -> fp16, a_s2/a_d2 ----------
#define GRID2 3072
__global__ __launch_bounds__(64) void k_gemm2(const float* __restrict__ xin, const float* __restrict__ W,
                                              const float* __restrict__ atts, const float* __restrict__ attd,
                                              __half* __restrict__ h2, float* __restrict__ a_s,
                                              float* __restrict__ a_d) {
    __shared__ float xs[8][128];
    int j = threadIdx.x;
    float wr[128];
#pragma unroll
    for (int k = 0; k < 128; ++k) wr[k] = W[k * 64 + j];
    float asj = atts[j], adj = attd[j];
    for (int n0 = blockIdx.x * 8; n0 < N_NODES; n0 += GRID2 * 8) {
        __syncthreads();
        {
            const float4* src = (const float4*)(xin + (size_t)n0 * 128);  // 256 float4
            float4* dst = (float4*)&xs[0][0];
#pragma unroll
            for (int q = 0; q < 4; ++q) dst[j + 64 * q] = src[j + 64 * q];
        }
        __syncthreads();
#pragma unroll 2
        for (int g = 0; g < 8; ++g) {
            int n = n0 + g;
            float a = 0.f;
#pragma unroll
            for (int k = 0; k < 128; ++k) a = fmaf(xs[g][k], wr[k], a);
            h2[(size_t)n * 64 + j] = __float2half(a);
            float ps = wred64(a * asj), pd = wred64(a * adj);
            if (j == 0) {
                a_s[n] = ps;
                a_d[n] = pd;
            }
        }
    }
}

// ---------- classifier node-side: P1 = hf@Wc1[0:64]+bc1, P2 = hf@Wc1[64:128] -> fp16 ----------
__global__ __launch_bounds__(64) void k_p12(const float* __restrict__ hf, const float* __restrict__ Wc1,
                                            const float* __restrict__ bc1, __half* __restrict__ P1,
                                            __half* __restrict__ P2) {
    __shared__ float xs[8][64];
    int j = threadIdx.x;
    float wr1[64], wr2[64];
#pragma unroll
    for (int k = 0; k < 64; ++k) {
        wr1[k] = Wc1[k * 64 + j];
        wr2[k] = Wc1[(64 + k) * 64 + j];
    }
    float bj = bc1[j];
    for (int n0 = blockIdx.x * 8; n0 < N_NODES; n0 += GRID2 * 8) {
        __syncthreads();
        {
            const float4* src = (const float4*)(hf + (size_t)n0 * 64);  // 128 float4 = 8 rows
            float4* dst = (float4*)&xs[0][0];
            dst[j] = src[j];
            dst[j + 64] = src[j + 64];
        }
        __syncthreads();
#pragma unroll 2
        for (int g = 0; g < 8; ++g) {
            int n = n0 + g;
            float a1 = bj, a2 = 0.f;
#pragma unroll
            for (int k = 0; k < 64; ++k) {
                a1 = fmaf(xs[g][k], wr1[k], a1);
                a2 = fmaf(xs[g][k], wr2[k], a2);
            }
            P1[(size_t)n * 64 + j] = __float2half(a1);
            P2[(size_t)n * 64 + j] = __float2half(a2);
        }
    }
}

// ---------- fused: scan stage 1 | edge attn contributions + fp16 copy of ea ----------
__global__ __launch_bounds__(256) void k_scan1_ae(const int* __restrict__ cnt, int* __restrict__ bsum,
                                                  const float* __restrict__ ea, const float* __restrict__ ve1,
                                                  const float* __restrict__ ve2, float* __restrict__ ae1,
                                                  float* __restrict__ ae2, __half* __restrict__ ea_h) {
    __shared__ int ws[4];
    int b = blockIdx.x;
    int t = threadIdx.x;
    if (b < SCAN_BLKS) {
        int idx = b * 256 + t;
        int v = (idx < N_NODES) ? cnt[idx] : 0;
        int w = wredi64(v);
        if ((t & 63) == 0) ws[t >> 6] = w;
        __syncthreads();
        if (t == 0) bsum[b] = ws[0] + ws[1] + ws[2] + ws[3];
    } else {
        int e = (b - SCAN_BLKS) * 256 + t;
        if (e >= N_EDGES) return;
        float s0 = 0.f, s1 = 0.f, s2 = 0.f;
#pragma unroll
        for (int k = 0; k < 16; ++k) {
            float v = ea[e * 16 + k];
            ea_h[(size_t)e * 16 + k] = __float2half(v);
            s0 = fmaf(v, ve1[k * 2 + 0], s0);
            s1 = fmaf(v, ve1[k * 2 + 1], s1);
            s2 = fmaf(v, ve2[k], s2);
        }
        ae1[e * 2 + 0] = s0;
        ae1[e * 2 + 1] = s1;
        ae2[e] = s2;
    }
}

// ---------- scan stage 3 with self-scanned block offsets ----------
__global__ __launch_bounds__(256) void k_scan3b(const int* __restrict__ cnt, const int* __restrict__ bsum,
                                                int* __restrict__ rp, int* __restrict__ cursor) {
    __shared__ int sb[256];
    __shared__ int sh[256];
    int t = threadIdx.x;
    int bv = (t < SCAN_BLKS) ? bsum[t] : 0;
    sb[t] = bv;
    __syncthreads();
    for (int off = 1; off < 256; off <<= 1) {
        int u = (t >= off) ? sb[t - off] : 0;
        __syncthreads();
        sb[t] += u;
        __syncthreads();
    }
    int blkoff = (blockIdx.x > 0) ? sb[blockIdx.x - 1] : 0;
    int idx = blockIdx.x * 256 + t;
    int v = (idx < N_NODES) ? cnt[idx] : 0;
    sh[t] = v;
    __syncthreads();
    for (int off = 1; off < 256; off <<= 1) {
        int u = (t >= off) ? sh[t - off] : 0;
        __syncthreads();
        sh[t] += u;
        __syncthreads();
    }
    if (idx < N_NODES) {
        int excl = blkoff + sh[t] - v;
        rp[idx] = excl;
        cursor[idx] = excl;
        if (idx == N_NODES - 1) rp[N_NODES] = excl + v;
    }
}

// ---------- fused CSR fill + CSR-ordered edge tables ----------
__global__ void k_fillprep1(const int* __restrict__ dst, const int* __restrict__ src,
                            int* __restrict__ cursor, const float* __restrict__ as1,
                            const float* __restrict__ ae1, int* __restrict__ eord,
                            int* __restrict__ src_ord, float* __restrict__ zo1) {
    int e = blockIdx.x * blockDim.x + threadIdx.x;
    if (e >= N_EDGES) return;
    int p = atomicAdd(&cursor[dst[e]], 1);
    int s = src[e];
    eord[p] = e;
    src_ord[p] = s;
    zo1[p * 2 + 0] = as1[s * 2 + 0] + ae1[e * 2 + 0];
    zo1[p * 2 + 1] = as1[s * 2 + 1] + ae1[e * 2 + 1];
}

__global__ void k_prep2(const int* __restrict__ eord, const int* __restrict__ src_ord,
                        const float* __restrict__ as2, const float* __restrict__ ae2,
                        float* __restrict__ zo2) {
    int i = blockIdx.x * blockDim.x + threadIdx.x;
    if (i >= N_EDGES) return;
    zo2[i] = as2[src_ord[i]] + ae2[eord[i]];
}

// ---------- fused per-dst softmax + gather aggregation + bias + ELU ----------
// Barrier-free; normalizer applied post-accumulation; hfeat gathered as fp16.
template <int C, int H>
__global__ __launch_bounds__(C) void k_attn_gather(const int* __restrict__ rp, const int* __restrict__ src_ord,
                                                   const float* __restrict__ zo, const float* __restrict__ a_d,
                                                   const __half* __restrict__ hfeat, const float* __restrict__ bias,
                                                   float* __restrict__ outp) {
    int n = blockIdx.x;
    int tid = threadIdx.x;
    int beg = rp[n], end = rp[n + 1];
    const int hsel = (H == 2) ? (tid >> 6) : 0;
    float adn = a_d[n * H + hsel];
    float acc0 = 0.f, acc1 = 0.f, acc2 = 0.f, acc3 = 0.f;
    float sm0 = 0.f, sm1 = 0.f, sm2 = 0.f, sm3 = 0.f;
    int i = beg;
    for (; i + 3 < end; i += 4) {
        int s0 = src_ord[i], s1 = src_ord[i + 1], s2 = src_ord[i + 2], s3 = src_ord[i + 3];
        float z0 = zo[(size_t)i * H + hsel] + adn;
        float z1 = zo[(size_t)(i + 1) * H + hsel] + adn;
        float z2 = zo[(size_t)(i + 2) * H + hsel] + adn;
        float z3 = zo[(size_t)(i + 3) * H + hsel] + adn;
        z0 = z0 > 0.f ? z0 : NEG_SLOPE * z0;
        z1 = z1 > 0.f ? z1 : NEG_SLOPE * z1;
        z2 = z2 > 0.f ? z2 : NEG_SLOPE * z2;
        z3 = z3 > 0.f ? z3 : NEG_SLOPE * z3;
        float ex0 = __expf(z0), ex1 = __expf(z1), ex2 = __expf(z2), ex3 = __expf(z3);
        sm0 += ex0;
        sm1 += ex1;
        sm2 += ex2;
        sm3 += ex3;
        acc0 = fmaf(__half2float(hfeat[(size_t)s0 * C + tid]), ex0, acc0);
        acc1 = fmaf(__half2float(hfeat[(size_t)s1 * C + tid]), ex1, acc1);
        acc2 = fmaf(__half2float(hfeat[(size_t)s2 * C + tid]), ex2, acc2);
        acc3 = fmaf(__half2float(hfeat[(size_t)s3 * C + tid]), ex3, acc3);
    }
    for (; i < end; ++i) {
        int s0 = src_ord[i];
        float z0 = zo[(size_t)i * H + hsel] + adn;
        z0 = z0 > 0.f ? z0 : NEG_SLOPE * z0;
        float ex0 = __expf(z0);
        sm0 += ex0;
        acc0 = fmaf(__half2float(hfeat[(size_t)s0 * C + tid]), ex0, acc0);
    }
    float sm = (sm0 + sm1) + (sm2 + sm3);
    float acc = (acc0 + acc1) + (acc2 + acc3);
    float v = acc / (sm + 1e-16f) + bias[tid];
    outp[(size_t)n * C + tid] = v > 0.f ? v : expm1f(v);
}

// ---------- classifier edge-side: warp per dst segment, fp16 tables, ILP-4 ----------
__global__ __launch_bounds__(256) void k_final(const int* __restrict__ rp, const int* __restrict__ eord,
                                               const int* __restrict__ src_ord, const __half* __restrict__ ea,
                                               const __half* __restrict__ P1, const __half* __restrict__ P2,
                                               const float* __restrict__ Wc1, const float* __restrict__ Wc2,
                                               const float* __restrict__ bc2, float* __restrict__ out) {
    int tid = threadIdx.x;
    int lane = tid & 63;
    float wreg[16];
#pragma unroll
    for (int k = 0; k < 16; ++k) wreg[k] = Wc1[128 * 64 + k * 64 + lane];
    float w2 = Wc2[lane];
    float bc = bc2[0];
    int n = blockIdx.x * 4 + (tid >> 6);
    if (n >= N_NODES) return;
    int beg = __builtin_amdgcn_readfirstlane(rp[n]);
    int end = __builtin_amdgcn_readfirstlane(rp[n + 1]);
    if (beg >= end) return;
    float p2 = __half2float(P2[(size_t)n * 64 + lane]);
    int i = beg;
    for (; i + 3 < end; i += 4) {
        int e0 = __builtin_amdgcn_readfirstlane(eord[i]);
        int e1 = __builtin_amdgcn_readfirstlane(eord[i + 1]);
        int e2 = __builtin_amdgcn_readfirstlane(eord[i + 2]);
        int e3 = __builtin_amdgcn_readfirstlane(eord[i + 3]);
        int s0 = __builtin_amdgcn_readfirstlane(src_ord[i]);
        int s1 = __builtin_amdgcn_readfirstlane(src_ord[i + 1]);
        int s2 = __builtin_amdgcn_readfirstlane(src_ord[i + 2]);
        int s3 = __builtin_amdgcn_readfirstlane(src_ord[i + 3]);
        float h0 = p2 + __half2float(P1[(size_t)s0 * 64 + lane]);
        float h1 = p2 + __half2float(P1[(size_t)s1 * 64 + lane]);
        float h2 = p2 + __half2float(P1[(size_t)s2 * 64 + lane]);
        float h3 = p2 + __half2float(P1[(size_t)s3 * 64 + lane]);
        const __half* ea0 = ea + (size_t)e0 * 16;
        const __half* ea1 = ea + (size_t)e1 * 16;
        const __half* ea2 = ea + (size_t)e2 * 16;
        const __half* ea3 = ea + (size_t)e3 * 16;
#pragma unroll
        for (int k = 0; k < 16; ++k) {
            float wv = wreg[k];
            h0 = fmaf(__half2float(ea0[k]), wv, h0);
            h1 = fmaf(__half2float(ea1[k]), wv, h1);
            h2 = fmaf(__half2float(ea2[k]), wv, h2);
            h3 = fmaf(__half2float(ea3[k]), wv, h3);
        }
        h0 = fmaxf(h0, 0.f) * w2;
        h1 = fmaxf(h1, 0.f) * w2;
        h2 = fmaxf(h2, 0.f) * w2;
        h3 = fmaxf(h3, 0.f) * w2;
#pragma unroll
        for (int off = 32; off > 0; off >>= 1) {
            h0 += __shfl_xor(h0, off, 64);
            h1 += __shfl_xor(h1, off, 64);
            h2 += __shfl_xor(h2, off, 64);
            h3 += __shfl_xor(h3, off, 64);
        }
        if (lane == 0) {
            out[e0] = h0 + bc;
            out[e1] = h1 + bc;
            out[e2] = h2 + bc;
            out[e3] = h3 + bc;
        }
    }
    for (; i < end; ++i) {
        int e0 = __builtin_amdgcn_readfirstlane(eord[i]);
        int s0 = __builtin_amdgcn_readfirstlane(src_ord[i]);
        float h0 = p2 + __half2float(P1[(size_t)s0 * 64 + lane]);
        const __half* ea0 = ea + (size_t)e0 * 16;
#pragma unroll
        for (int k = 0; k < 16; ++k) h0 = fmaf(__half2float(ea0[k]), wreg[k], h0);
        h0 = fmaxf(h0, 0.f);
        float v = wred64(h0 * w2);
        if (lane == 0) out[e0] = v + bc;
    }
}

extern "C" void kernel_launch(void* const* d_in, const int* in_sizes, int n_in,
                              void* d_out, int out_size, void* d_ws, size_t ws_size,
                              hipStream_t stream) {
    const float* x     = (const float*)d_in[0];
    const int*   eidx  = (const int*)d_in[1];
    const float* ea    = (const float*)d_in[2];
    const float* W1    = (const float*)d_in[3];
    const float* atts1 = (const float*)d_in[4];
    const float* attd1 = (const float*)d_in[5];
    const float* We1   = (const float*)d_in[6];
    const float* atte1 = (const float*)d_in[7];
    const float* b1    = (const float*)d_in[8];
    const float* W2    = (const float*)d_in[9];
    const float* atts2 = (const float*)d_in[10];
    const float* attd2 = (const float*)d_in[11];
    const float* We2   = (const float*)d_in[12];
    const float* atte2 = (const float*)d_in[13];
    const float* b2    = (const float*)d_in[14];
    const float* Wc1   = (const float*)d_in[15];
    const float* bc1   = (const float*)d_in[16];
    const float* Wc2   = (const float*)d_in[17];
    const float* bc2   = (const float*)d_in[18];
    const int* srcp = eidx;
    const int* dstp = eidx + N_EDGES;
    float* out = (float*)d_out;

    char* w = (char*)d_ws;
    size_t off = 0;
    auto alloc = [&](size_t bytes) -> void* {
        void* p = w + off;
        off += (bytes + 255) & ~size_t(255);
        return p;
    };

    __half* h1h  = (__half*)alloc(N_NODES * 128 * sizeof(__half));  // conv1 features; later h2/P1/P2
    float* as1  = (float*)alloc(N_NODES * 2 * sizeof(float));
    float* ad1  = (float*)alloc(N_NODES * 2 * sizeof(float));
    float* ae1  = (float*)alloc(N_EDGES * 2 * sizeof(float));    // dead after k_fillprep1; reused as zo2
    float* ae2  = (float*)alloc(N_EDGES * sizeof(float));
    float* as2  = (float*)alloc(N_NODES * sizeof(float));
    float* ad2  = (float*)alloc(N_NODES * sizeof(float));
    float* ve1  = (float*)alloc(32 * sizeof(float));
    float* ve2  = (float*)alloc(16 * sizeof(float));
    int*   rp      = (int*)alloc((N_NODES + 1) * sizeof(int));
    int*   eord    = (int*)alloc(N_EDGES * sizeof(int));
    int*   cursor  = (int*)alloc(N_NODES * sizeof(int));
    int*   src_ord = (int*)alloc(N_EDGES * sizeof(int));
    float* zo1     = (float*)alloc(N_EDGES * 2 * sizeof(float));
    float* out1    = (float*)alloc(N_NODES * 128 * sizeof(float));
    __half* ea_h   = (__half*)alloc((size_t)N_EDGES * 16 * sizeof(__half));
    int*   bsum    = (int*)alloc(SCAN_BLKS * sizeof(int));

    // aliases (lifetime-disjoint)
    __half* h2h = h1h;                 // [N,64] fp16: gemm2 writes after h1's last read (gather1)
    __half* P1h = h1h;                 // [N,64] fp16: p12 writes after h2's last read (gather2)
    __half* P2h = h1h + (size_t)N_NODES * 64;
    float* zo2  = ae1;                 // [E]: prep2 writes after ae1's last read (fillprep1)
    float* out2 = out1;                // [N,64]: gather2 writes after out1's last read (gemm2)

    // zeroed-every-call region
    char* zstart = w + off;
    int* cnt = (int*)alloc(N_NODES * sizeof(int));
    size_t zbytes = (size_t)((w + off) - zstart);
    hipMemsetAsync(zstart, 0, zbytes, stream);

    const int EB = (N_EDGES + 255) / 256;  // 3125

    // L1: ve | dst histogram
    k_ve_hist<<<1 + EB, 256, 0, stream>>>(We1, atte1, We2, atte2, ve1, ve2, dstp, cnt);
    // L2: conv1 node GEMM (fp16 output)
    k_gemm1<<<GRID1, 128, 0, stream>>>(x, W1, atts1, attd1, h1h, as1, ad1);
    // L3: scan stage 1 | edge attn contributions + ea fp16 copy
    k_scan1_ae<<<SCAN_BLKS + EB, 256, 0, stream>>>(cnt, bsum, ea, ve1, ve2, ae1, ae2, ea_h);
    // L4: scan stage 3 -> rp, cursor
    k_scan3b<<<SCAN_BLKS, 256, 0, stream>>>(cnt, bsum, rp, cursor);
    // L5: CSR fill + CSR-ordered tables (eord, src_ord, zo1)
    k_fillprep1<<<EB, 256, 0, stream>>>(dstp, srcp, cursor, as1, ae1, eord, src_ord, zo1);
    // L6: conv1 fused softmax+aggregate+bias+ELU (fp16 gather)
    k_attn_gather<128, 2><<<N_NODES, 128, 0, stream>>>(rp, src_ord, zo1, ad1, h1h, b1, out1);
    // L7-L9: conv2
    k_gemm2<<<GRID2, 64, 0, stream>>>(out1, W2, atts2, attd2, h2h, as2, ad2);
    k_prep2<<<EB, 256, 0, stream>>>(eord, src_ord, as2, ae2, zo2);
    k_attn_gather<64, 1><<<N_NODES, 64, 0, stream>>>(rp, src_ord, zo2, ad2, h2h, b2, out2);
    // L10-L11: edge classifier (fp16 tables)
    k_p12<<<GRID2, 64, 0, stream>>>(out2, Wc1, bc1, P1h, P2h);
    k_final<<<(N_NODES + 3) / 4, 256, 0, stream>>>(rp, eord, src_ord, ea_h, P1h, P2h, Wc1, Wc2, bc2, out);
}